// Round 1
// baseline (157084.741 us; speedup 1.0000x reference)
//
#include <hip/hip_runtime.h>
#include <math.h>

// ---------------------------------------------------------------------------
// MIM video-prediction RNN, fp32 correctness-first baseline.
// B=8, hidden NH=64, spatial 32x32 (patchified 128x128/4), 19 time steps.
// ---------------------------------------------------------------------------

#define NTOT 524288   // 8*64*1024  (one 64-ch state tensor)

__device__ __forceinline__ float sigf(float x) { return 1.0f / (1.0f + expf(-x)); }

// ---------------- conv 5x5, pad 2, on [B][Cin][32][32] -> [B][Cout][32][32] --
// block = 256 threads: one (b, 16-out-channel tile), all 1024 pixels.
// thread: 4 pixels (rows y0, y0+8, y0+16, y0+24) x 16 co accumulators.
__global__ __launch_bounds__(256) void conv5_f32(
    const float* __restrict__ in, const float* __restrict__ wgt,
    float* __restrict__ out, int Cin, int Cout, int coBlocks) {
  int blk = blockIdx.x;
  int b = blk / coBlocks;
  int coB = (blk - b * coBlocks) * 16;
  int tid = threadIdx.x;
  __shared__ float s_in[36 * 36];
  __shared__ float s_w[25][16];
  float acc[4][16];
#pragma unroll
  for (int j = 0; j < 4; ++j)
#pragma unroll
    for (int c = 0; c < 16; ++c) acc[j][c] = 0.f;

  const float* inb = in + (size_t)b * Cin * 1024;
  int y0 = tid >> 5, x0 = tid & 31;

  for (int ci = 0; ci < Cin; ++ci) {
    const float* p = inb + (size_t)ci * 1024;
    for (int idx = tid; idx < 1296; idx += 256) {
      int r = idx / 36, cc2 = idx - r * 36;
      int yy = r - 2, xx = cc2 - 2;
      float v = 0.f;
      if ((unsigned)yy < 32u && (unsigned)xx < 32u) v = p[(yy << 5) + xx];
      s_in[idx] = v;
    }
    {
      const float* wp = wgt + ((size_t)coB * Cin + ci) * 25;
      for (int idx = tid; idx < 400; idx += 256) {
        int c = idx / 25, k = idx - c * 25;
        s_w[k][c] = wp[(size_t)c * Cin * 25 + k];
      }
    }
    __syncthreads();
#pragma unroll
    for (int k = 0; k < 25; ++k) {
      int dy = k / 5, dx = k - dy * 5;
      float v0 = s_in[(y0 + dy) * 36 + x0 + dx];
      float v1 = s_in[(y0 + 8 + dy) * 36 + x0 + dx];
      float v2 = s_in[(y0 + 16 + dy) * 36 + x0 + dx];
      float v3 = s_in[(y0 + 24 + dy) * 36 + x0 + dx];
#pragma unroll
      for (int c = 0; c < 16; ++c) {
        float wv = s_w[k][c];
        acc[0][c] = fmaf(wv, v0, acc[0][c]);
        acc[1][c] = fmaf(wv, v1, acc[1][c]);
        acc[2][c] = fmaf(wv, v2, acc[2][c]);
        acc[3][c] = fmaf(wv, v3, acc[3][c]);
      }
    }
    __syncthreads();
  }
  float* ob = out + ((size_t)b * Cout + coB) * 1024 + tid;
#pragma unroll
  for (int c = 0; c < 16; ++c)
#pragma unroll
    for (int j = 0; j < 4; ++j) ob[(size_t)c * 1024 + j * 256] = acc[j][c];
}

// ---------------- conv 1x1 on [B][Cin][32][32] -> [B][Cout][32][32] ---------
// grid = B * 4(pixel blocks) * coBlocks; thread: 1 pixel x 16 co.
__global__ __launch_bounds__(256) void conv1_f32(
    const float* __restrict__ in, const float* __restrict__ wgt,
    float* __restrict__ out, int Cin, int Cout, int coBlocks) {
  int blk = blockIdx.x;
  int coIdx = blk % coBlocks;
  int rest = blk / coBlocks;
  int pb = rest & 3;
  int b = rest >> 2;
  int coB = coIdx * 16;
  int tid = threadIdx.x;
  int p = pb * 256 + tid;
  __shared__ float s_w[128 * 16];
  for (int idx = tid; idx < Cin * 16; idx += 256) {
    int ci = idx >> 4, c = idx & 15;
    s_w[idx] = wgt[(size_t)(coB + c) * Cin + ci];
  }
  __syncthreads();
  float acc[16];
#pragma unroll
  for (int c = 0; c < 16; ++c) acc[c] = 0.f;
  const float* ib = in + (size_t)b * Cin * 1024 + p;
  for (int ci = 0; ci < Cin; ++ci) {
    float v = ib[(size_t)ci * 1024];
#pragma unroll
    for (int c = 0; c < 16; ++c) acc[c] = fmaf(s_w[(ci << 4) + c], v, acc[c]);
  }
  float* ob = out + ((size_t)b * Cout + coB) * 1024 + p;
#pragma unroll
  for (int c = 0; c < 16; ++c) ob[(size_t)c * 1024] = acc[c];
}

// ---------------- net input: patchify frames0 or take x_gen -----------------
// net[b][ch][y][x], ch = py*4+px ; 131072 elements.
__global__ void build_net_k(const float* __restrict__ frames0,
                            const float* __restrict__ xgen,
                            float* __restrict__ net, int t) {
  int idx = blockIdx.x * 256 + threadIdx.x;
  int b = idx >> 14, ch = (idx >> 10) & 15, p = idx & 1023;
  int y = p >> 5, x = p & 31, py = ch >> 2, px = ch & 3;
  float v;
  if (t < 10)
    v = frames0[((size_t)b * 10 + t) * 16384 + (y * 4 + py) * 128 + (x * 4 + px)];
  else
    v = xgen[idx];
  net[idx] = v;
}

// ---------------- un-patchify x_gen into output frame f ---------------------
__global__ void write_out_k(const float* __restrict__ xgen, float* __restrict__ out,
                            int f) {
  int idx = blockIdx.x * 256 + threadIdx.x;
  int b = idx >> 14, ch = (idx >> 10) & 15, p = idx & 1023;
  int y = p >> 5, x = p & 31, py = ch >> 2, px = ch & 3;
  out[((size_t)b * 10 + f) * 16384 + (y * 4 + py) * 128 + (x * 4 + px)] = xgen[idx];
}

// ---------------- ST-LSTM gates ---------------------------------------------
// xc: [B][448][1024] chunks (i_x,f_x,g_x,i_xp,f_xp,g_xp,o_x)
// hc: [B][256][1024] chunks (i_h,f_h,g_h,o_h); mc: [B][192][1024] (i_m,f_m,g_m)
__global__ void st_gate1_k(const float* __restrict__ xc, const float* __restrict__ hc,
                           const float* __restrict__ mc, float* __restrict__ c,
                           float* __restrict__ m, float* __restrict__ pack) {
  int idx = blockIdx.x * 256 + threadIdx.x;
  int b = idx >> 16, r = idx & 65535;
  const float* xb = xc + (size_t)b * 458752 + r;
  const float* hb = hc + (size_t)b * 262144 + r;
  const float* mb = mc + (size_t)b * 196608 + r;
  float i_x = xb[0], f_x = xb[65536], g_x = xb[131072];
  float i_xp = xb[196608], f_xp = xb[262144], g_xp = xb[327680];
  float i_h = hb[0], f_h = hb[65536], g_h = hb[131072];
  float i_m = mb[0], f_m = mb[65536], g_m = mb[131072];
  float c0 = c[idx], m0 = m[idx];
  float cn = sigf(f_x + f_h + 1.0f) * c0 + sigf(i_x + i_h) * tanhf(g_x + g_h);
  float mn = sigf(f_xp + f_m + 1.0f) * m0 + sigf(i_xp + i_m) * tanhf(g_xp + g_m);
  c[idx] = cn;
  m[idx] = mn;
  float* pb2 = pack + (size_t)b * 131072 + r;
  pb2[0] = cn;
  pb2[65536] = mn;
}

__global__ void st_gate2_k(const float* __restrict__ xc, const float* __restrict__ hc,
                           const float* __restrict__ oc, const float* __restrict__ lc,
                           float* __restrict__ h, float* __restrict__ diff) {
  int idx = blockIdx.x * 256 + threadIdx.x;
  int b = idx >> 16, r = idx & 65535;
  float o_x = xc[(size_t)b * 458752 + 393216 + r];
  float o_h = hc[(size_t)b * 262144 + 196608 + r];
  float o = sigf(o_x + o_h + oc[idx]);
  float hn = o * tanhf(lc[idx]);
  float old = h[idx];
  h[idx] = hn;
  diff[idx] = hn - old;
}

// ---------------- MIMN gate (gated(): split order i,g,f,o) ------------------
__global__ void mimn_gate_k(const float* __restrict__ hcv, const float* __restrict__ xcv,
                            float* __restrict__ dh, float* __restrict__ dc,
                            const float* __restrict__ ctw, const float* __restrict__ ocw) {
  int idx = blockIdx.x * 256 + threadIdx.x;
  int b = idx >> 16, r = idx & 65535;
  const float* hb = hcv + (size_t)b * 262144 + r;
  const float* xb = xcv + (size_t)b * 262144 + r;
  float i_h = hb[0], g_h = hb[65536], f_h = hb[131072], o_h = hb[196608];
  float i_x = xb[0], g_x = xb[65536], f_x = xb[131072], o_x = xb[196608];
  float c0 = dc[idx];
  float i_c = c0 * ctw[r], f_c = c0 * ctw[65536 + r];
  float cn = sigf(f_h + f_c + f_x + 1.0f) * c0 + sigf(i_h + i_c + i_x) * tanhf(g_h + g_x);
  float hn = sigf(o_h + o_x + cn * ocw[r]) * tanhf(cn);
  dc[idx] = cn;
  dh[idx] = hn;
}

// ---------------- MIMBlock gate 1 -------------------------------------------
// sc(256: i,g,f,o), tc(192: i,g,o), xcv(256: i,g,f,o), mhc/mxc(256: i,g,f,o)
__global__ void mimblock_gate1_k(const float* __restrict__ sc, const float* __restrict__ tc,
                                 const float* __restrict__ xcv, const float* __restrict__ mhc,
                                 const float* __restrict__ mxc, float* __restrict__ m,
                                 float* __restrict__ c, float* __restrict__ ccb,
                                 const float* __restrict__ ctw, const float* __restrict__ ocw,
                                 float* __restrict__ cell, float* __restrict__ osum) {
  int idx = blockIdx.x * 256 + threadIdx.x;
  int b = idx >> 16, r = idx & 65535;
  const float* sb = sc + (size_t)b * 262144 + r;
  const float* tb = tc + (size_t)b * 196608 + r;
  const float* xb = xcv + (size_t)b * 262144 + r;
  const float* mh = mhc + (size_t)b * 262144 + r;
  const float* mx = mxc + (size_t)b * 262144 + r;
  float i_s = sb[0], g_s = sb[65536], f_s = sb[131072], o_s = sb[196608];
  float i_t = tb[0], g_t = tb[65536], o_t = tb[131072];
  float i_x = xb[0], g_x = xb[65536], f_x = xb[131072], o_x = xb[196608];
  float m0 = m[idx];
  float nm = sigf(f_x + f_s + 1.0f) * m0 + sigf(i_x + i_s) * tanhf(g_x + g_s);
  float h_i = mh[0], h_g = mh[65536], h_f = mh[131072], h_o = mh[196608];
  float x_i = mx[0], x_g = mx[65536], x_f = mx[131072], x_o = mx[196608];
  float cc0 = ccb[idx];
  float i_c = cc0 * ctw[r], f_c = cc0 * ctw[65536 + r];
  float mims_c =
      sigf(h_f + f_c + x_f + 1.0f) * cc0 + sigf(h_i + i_c + x_i) * tanhf(h_g + x_g);
  float c2 = sigf(h_o + x_o + mims_c * ocw[r]) * tanhf(mims_c);
  float nc = c2 + sigf(i_x + i_t) * tanhf(g_x + g_t);
  m[idx] = nm;
  c[idx] = nc;
  ccb[idx] = mims_c;
  float* cb = cell + (size_t)b * 131072 + r;
  cb[0] = nc;
  cb[65536] = nm;
  osum[idx] = o_x + o_t + o_s;
}

__global__ void mimblock_gate2_k(const float* __restrict__ osum,
                                 const float* __restrict__ lc, float* __restrict__ h) {
  int idx = blockIdx.x * 256 + threadIdx.x;
  h[idx] = sigf(osum[idx]) * tanhf(lc[idx]);
}

// ---------------------------------------------------------------------------
extern "C" void kernel_launch(void* const* d_in, const int* in_sizes, int n_in,
                              void* d_out, int out_size, void* d_ws, size_t ws_size,
                              hipStream_t stream) {
  const float* frames0 = (const float*)d_in[0];
  // d_in[1] = frames1: never used (use_frame is False for t>=10)
  const float* st_cx = (const float*)d_in[2];
  const float* st_ch = (const float*)d_in[3];
  const float* st_cm = (const float*)d_in[4];
  const float* st_co = (const float*)d_in[5];
  const float* st_cl = (const float*)d_in[6];
  const float* mb_t = (const float*)d_in[7];
  const float* mb_s = (const float*)d_in[8];
  const float* mb_x = (const float*)d_in[9];
  const float* mb_mh = (const float*)d_in[10];
  const float* mb_mx = (const float*)d_in[11];
  const float* mb_ctw = (const float*)d_in[12];
  const float* mb_ocw = (const float*)d_in[13];
  const float* mb_last = (const float*)d_in[14];
  const float* mn_ch = (const float*)d_in[15];
  const float* mn_cx = (const float*)d_in[16];
  const float* mn_ctw = (const float*)d_in[17];
  const float* mn_ocw = (const float*)d_in[18];
  const float* w_last = (const float*)d_in[19];
  float* out = (float*)d_out;

  float* ws = (float*)d_ws;
  size_t off = 0;
  auto A = [&](size_t n) {
    float* p = ws + off;
    off += n;
    return p;
  };
  const size_t S = NTOT;
  float* hs[4];
  for (int i = 0; i < 4; ++i) hs[i] = A(S);
  float* cs[4];
  for (int i = 0; i < 4; ++i) cs[i] = A(S);
  float* memb = A(S);
  float* dh[3];
  for (int i = 0; i < 3; ++i) dh[i] = A(S);
  float* dcb[3];
  for (int i = 0; i < 3; ++i) dcb[i] = A(S);
  float* ccb[3];
  for (int i = 0; i < 3; ++i) ccb[i] = A(S);
  float* diffb = A(S);
  float* zerosb = A(S);
  size_t zeroFloats = off;  // states + diff + zeros get zeroed each launch
  float* xgen = A(131072);
  float* netb = A(131072);
  float* osum = A(S);
  float* pack = A(1048576);     // 128-ch concat buffer (mem2 / cell)
  float* t448 = A(3670016);
  float* t256a = A(2097152);
  float* t256b = A(2097152);
  float* t256c = A(2097152);
  float* t256d = A(2097152);
  float* t192 = A(1572864);
  float* t64a = A(S);
  float* t64b = A(S);
  if (ws_size < off * sizeof(float)) return;  // workspace too small

  hipMemsetAsync(ws, 0, zeroFloats * sizeof(float), stream);

  auto conv5 = [&](const float* in, const float* w, float* o, int Cin, int Cout) {
    conv5_f32<<<dim3(8 * (Cout / 16)), dim3(256), 0, stream>>>(in, w, o, Cin, Cout,
                                                               Cout / 16);
  };
  auto conv1 = [&](const float* in, const float* w, float* o, int Cin, int Cout) {
    conv1_f32<<<dim3(8 * 4 * (Cout / 16)), dim3(256), 0, stream>>>(in, w, o, Cin, Cout,
                                                                   Cout / 16);
  };

  for (int t = 0; t < 19; ++t) {
    build_net_k<<<dim3(512), dim3(256), 0, stream>>>(frames0, xgen, netb, t);
    // ---- ST-LSTM (layer 0) ----
    conv5(netb, st_cx, t448, 16, 448);
    conv5(hs[0], st_ch, t256a, 64, 256);
    conv5(memb, st_cm, t192, 64, 192);
    st_gate1_k<<<dim3(2048), dim3(256), 0, stream>>>(t448, t256a, t192, cs[0], memb,
                                                     pack);
    conv5(pack, st_co, t64a, 128, 64);
    conv1(pack, st_cl, t64b, 128, 64);
    st_gate2_k<<<dim3(2048), dim3(256), 0, stream>>>(t448, t256a, t64a, t64b, hs[0],
                                                     diffb);
    // ---- layers 1..3 ----
    for (int i = 1; i < 4; ++i) {
      int li = i - 1;
      if (t >= 1) {
        const float* din = (i == 1) ? diffb : dh[i - 2];
        conv5(dh[li], mn_ch + (size_t)li * 409600, t256a, 64, 256);
        conv5(din, mn_cx + (size_t)li * 409600, t256b, 64, 256);
        mimn_gate_k<<<dim3(2048), dim3(256), 0, stream>>>(
            t256a, t256b, dh[li], dcb[li], mn_ctw + (size_t)li * 131072,
            mn_ocw + (size_t)li * 65536);
      }
      const float* diffh = (t == 0) ? zerosb : dh[li];
      conv5(memb, mb_s + (size_t)li * 409600, t256a, 64, 256);
      conv5(hs[i], mb_t + (size_t)li * 307200, t192, 64, 192);
      conv5(hs[i - 1], mb_x + (size_t)li * 409600, t256b, 64, 256);
      conv5(cs[i], mb_mh + (size_t)li * 409600, t256c, 64, 256);
      conv5(diffh, mb_mx + (size_t)li * 409600, t256d, 64, 256);
      mimblock_gate1_k<<<dim3(2048), dim3(256), 0, stream>>>(
          t256a, t192, t256b, t256c, t256d, memb, cs[i], ccb[li],
          mb_ctw + (size_t)li * 131072, mb_ocw + (size_t)li * 65536, pack, osum);
      conv1(pack, mb_last + (size_t)li * 8192, t64a, 128, 64);
      mimblock_gate2_k<<<dim3(2048), dim3(256), 0, stream>>>(osum, t64a, hs[i]);
    }
    conv1(hs[3], w_last, xgen, 64, 16);
    if (t >= 9) write_out_k<<<dim3(512), dim3(256), 0, stream>>>(xgen, out, t - 9);
  }
}